// Round 1
// baseline (938.589 us; speedup 1.0000x reference)
//
#include <hip/hip_runtime.h>
#include <hip/hip_bf16.h>
#include <cstdint>
#include <cstddef>

// FocusedLinearAttention on MI355X (gfx950).
// Pipeline:
//  1. cvt x, qkv_w, proj_w -> bf16
//  2. prep_scale: inv_sc = 1/softplus(scale)
//  3. gemm_qkv (bf16 MFMA, A@B^T): q,k -> fp32 ws, v -> bf16 ws
//  4. transform: relu+eps, /sc, cube-renormalize (norms over full C=1024) -> q',k' bf16
//  5. kv_partial (8-way N split) + reduce: ksum[bh][64], kv[bh][64][64] fp32
//  6. z_o: z = 1/(q'.ksum+eps); o = z * q' @ kv -> bf16 (B,N,C)
//  7. gemm_proj (bf16 MFMA) + bias -> fp32 out

typedef __bf16 bf16;
typedef __bf16 bf16x4 __attribute__((ext_vector_type(4)));
typedef __bf16 bf16x8 __attribute__((ext_vector_type(8)));
typedef float f32x4 __attribute__((ext_vector_type(4)));

#define NB 8
#define NSEQ 4096
#define NC 1024
#define NH 16
#define ND 64
#define NBH 128      // NB*NH
#define NM 32768     // NB*NSEQ
#define EPSF 1e-6f
#define KSPLIT 8

__device__ __forceinline__ void async16(const void* g, void* l) {
  __builtin_amdgcn_global_load_lds(
      (const __attribute__((address_space(1))) void*)g,
      (__attribute__((address_space(3))) void*)l, 16, 0, 0);
}

// ---------------- fp32 -> bf16 convert ----------------
__global__ __launch_bounds__(256) void cvt_bf16(const float* __restrict__ src,
                                                bf16* __restrict__ dst, int n4) {
  int i = blockIdx.x * 256 + threadIdx.x;
  if (i < n4) {
    f32x4 v = ((const f32x4*)src)[i];
    bf16x4 o;
    o[0] = (bf16)v[0]; o[1] = (bf16)v[1]; o[2] = (bf16)v[2]; o[3] = (bf16)v[3];
    ((bf16x4*)dst)[i] = o;
  }
}

// ---------------- inv softplus(scale) ----------------
__global__ __launch_bounds__(256) void prep_scale(const float* __restrict__ scale,
                                                  float* __restrict__ inv_sc) {
  int c = blockIdx.x * 256 + threadIdx.x;
  if (c < NC) inv_sc[c] = 1.0f / log1pf(expf(scale[c]));
}

// ---------------- 128x128 bf16 MFMA GEMM, C = A @ B^T ----------------
// A: (M x K) bf16 row-major, Bm: (N x K) bf16 row-major. K % 32 == 0.
// MODE 0: qkv split  (col < 2048 -> fp32 outf width 2048; col >= 2048 -> bf16 outb width 1024)
// MODE 1: fp32 out width 1024, += bias
template <int MODE>
__global__ __launch_bounds__(256) void gemm_bt(const bf16* __restrict__ A,
                                               const bf16* __restrict__ Bm, int K,
                                               float* __restrict__ outf,
                                               bf16* __restrict__ outb,
                                               const float* __restrict__ bias) {
  __shared__ bf16 As[128 * 32];
  __shared__ bf16 Bs[128 * 32];
  const int tid = threadIdx.x;
  const int w = tid >> 6, lane = tid & 63;
  const int wm = (w >> 1) * 64, wn = (w & 1) * 64;
  const int q4 = lane >> 4, l16 = lane & 15;
  const long row0 = (long)blockIdx.y * 128, col0 = (long)blockIdx.x * 128;

  const int rA = w * 32 + (lane >> 2);   // staged row (chunk w*2), +16 for chunk w*2+1
  const int kkc = (lane & 3) * 8;        // k element offset within 32-wide tile
  const bf16* Ag = A + (row0 + rA) * (long)K + kkc;
  const bf16* Bg = Bm + (col0 + rA) * (long)K + kkc;
  bf16* Al = As + w * 1024 + lane * 8;
  bf16* Bl = Bs + w * 1024 + lane * 8;

  f32x4 acc[4][4] = {};

  for (int k0 = 0; k0 < K; k0 += 32) {
    async16(Ag + k0, Al);
    async16(Ag + 16 * (long)K + k0, Al + 512);
    async16(Bg + k0, Bl);
    async16(Bg + 16 * (long)K + k0, Bl + 512);
    __syncthreads();
    bf16x8 af[4], bfr[4];
#pragma unroll
    for (int mi = 0; mi < 4; mi++)
      af[mi] = *(const bf16x8*)(As + (wm + mi * 16 + l16) * 32 + q4 * 8);
#pragma unroll
    for (int ni = 0; ni < 4; ni++)
      bfr[ni] = *(const bf16x8*)(Bs + (wn + ni * 16 + l16) * 32 + q4 * 8);
#pragma unroll
    for (int mi = 0; mi < 4; mi++)
#pragma unroll
      for (int ni = 0; ni < 4; ni++)
        acc[mi][ni] = __builtin_amdgcn_mfma_f32_16x16x32_bf16(af[mi], bfr[ni],
                                                              acc[mi][ni], 0, 0, 0);
    __syncthreads();
  }

#pragma unroll
  for (int mi = 0; mi < 4; mi++) {
    long gr0 = row0 + wm + mi * 16 + q4 * 4;
#pragma unroll
    for (int ni = 0; ni < 4; ni++) {
      long gc = col0 + wn + ni * 16 + l16;
#pragma unroll
      for (int r = 0; r < 4; r++) {
        float v = acc[mi][ni][r];
        long gr = gr0 + r;
        if (MODE == 0) {
          if (gc < 2048) outf[gr * 2048 + gc] = v;
          else outb[gr * 1024 + (gc - 2048)] = (bf16)v;
        } else {
          outf[gr * 1024 + gc] = v + bias[gc];
        }
      }
    }
  }
}

// ---------------- q/k nonlinear transform (per row over C=1024) ----------------
__global__ __launch_bounds__(256) void transform_qk(const float* __restrict__ qk,
                                                    const float* __restrict__ pos_enc,
                                                    const float* __restrict__ inv_sc,
                                                    bf16* __restrict__ qp,
                                                    bf16* __restrict__ kp) {
  __shared__ f32x4 red[4];
  const long row = blockIdx.x;          // 0..NM-1
  const int n = (int)(row & (NSEQ - 1));
  const int c0 = threadIdx.x * 4;

  f32x4 q = *(const f32x4*)(qk + row * 2048 + c0);
  f32x4 k = *(const f32x4*)(qk + row * 2048 + 1024 + c0);
  f32x4 pe = *(const f32x4*)(pos_enc + (long)n * 1024 + c0);
  f32x4 isc = *(const f32x4*)(inv_sc + c0);

  f32x4 q3, k3;
  float s2q = 0, s6q = 0, s2k = 0, s6k = 0;
#pragma unroll
  for (int j = 0; j < 4; j++) {
    float qv = (fmaxf(q[j], 0.f) + EPSF) * isc[j];
    float kv = (fmaxf(k[j] + pe[j], 0.f) + EPSF) * isc[j];
    float q3v = qv * qv * qv, k3v = kv * kv * kv;
    q3[j] = q3v; k3[j] = k3v;
    s2q += qv * qv; s6q += q3v * q3v;
    s2k += kv * kv; s6k += k3v * k3v;
  }
  f32x4 s; s[0] = s2q; s[1] = s6q; s[2] = s2k; s[3] = s6k;
#pragma unroll
  for (int off = 32; off > 0; off >>= 1) {
    s[0] += __shfl_xor(s[0], off);
    s[1] += __shfl_xor(s[1], off);
    s[2] += __shfl_xor(s[2], off);
    s[3] += __shfl_xor(s[3], off);
  }
  const int wv = threadIdx.x >> 6;
  if ((threadIdx.x & 63) == 0) red[wv] = s;
  __syncthreads();
  f32x4 tot = red[0] + red[1] + red[2] + red[3];
  float fq = sqrtf(tot[0] / tot[1]);
  float fk = sqrtf(tot[2] / tot[3]);

  bf16x4 qo, ko;
#pragma unroll
  for (int j = 0; j < 4; j++) {
    qo[j] = (bf16)(q3[j] * fq);
    ko[j] = (bf16)(k3[j] * fk);
  }
  *(bf16x4*)(qp + row * 1024 + c0) = qo;
  *(bf16x4*)(kp + row * 1024 + c0) = ko;
}

// ---------------- kv = k^T v and ksum, partial over N/KSPLIT rows ----------------
__global__ __launch_bounds__(256) void kv_partial(const bf16* __restrict__ kp,
                                                  const bf16* __restrict__ vb,
                                                  float* __restrict__ kv_part,
                                                  float* __restrict__ ks_part) {
  __shared__ float kls[64 * 64];
  __shared__ float vls[64 * 64];
  const int sp = blockIdx.x;       // 0..KSPLIT-1
  const int bh = blockIdx.y;       // 0..127
  const int b = bh >> 4, h = bh & 15;
  const int tid = threadIdx.x;
  const int c0 = (tid & 15) * 4, d0 = (tid >> 4) * 4;

  f32x4 acc4[4] = {};
  float ks[4] = {0.f, 0.f, 0.f, 0.f};

  for (int chunk = 0; chunk < NSEQ / KSPLIT / 64; ++chunk) {
    const int n0 = sp * (NSEQ / KSPLIT) + chunk * 64;
    __syncthreads();
    for (int it = tid; it < 1024; it += 256) {
      int nn = it >> 4, cc = (it & 15) * 4;
      long g = ((long)(b * NSEQ + n0 + nn)) * NC + h * ND + cc;
      bf16x4 kb = *(const bf16x4*)(kp + g);
      bf16x4 vv = *(const bf16x4*)(vb + g);
      f32x4 kf, vf;
#pragma unroll
      for (int j = 0; j < 4; j++) { kf[j] = (float)kb[j]; vf[j] = (float)vv[j]; }
      *(f32x4*)&kls[nn * 64 + cc] = kf;
      *(f32x4*)&vls[nn * 64 + cc] = vf;
    }
    __syncthreads();
    for (int nn = 0; nn < 64; ++nn) {
      f32x4 kk = *(const f32x4*)&kls[nn * 64 + c0];
      f32x4 vv = *(const f32x4*)&vls[nn * 64 + d0];
#pragma unroll
      for (int i = 0; i < 4; i++) acc4[i] += kk[i] * vv;
      if (tid < 16) {
#pragma unroll
        for (int i = 0; i < 4; i++) ks[i] += kk[i];
      }
    }
  }
  const long base = ((long)(sp * NBH + bh)) * 4096;
#pragma unroll
  for (int i = 0; i < 4; i++)
    *(f32x4*)&kv_part[base + (c0 + i) * 64 + d0] = acc4[i];
  if (tid < 16) {
#pragma unroll
    for (int i = 0; i < 4; i++)
      ks_part[(long)(sp * NBH + bh) * 64 + c0 + i] = ks[i];
  }
}

__global__ __launch_bounds__(256) void reduce_parts(const float* __restrict__ src,
                                                    float* __restrict__ dst, int n) {
  int i = blockIdx.x * 256 + threadIdx.x;
  if (i < n) {
    float s = 0.f;
    for (int p = 0; p < KSPLIT; ++p) s += src[(long)p * n + i];
    dst[i] = s;
  }
}

// ---------------- z + o = z * q' @ kv ----------------
__global__ __launch_bounds__(256) void z_o(const bf16* __restrict__ qp,
                                           const float* __restrict__ kvm,
                                           const float* __restrict__ ksum,
                                           bf16* __restrict__ ob) {
  __shared__ float kvs[4096];
  __shared__ float kss[64];
  const int bh = blockIdx.x >> 4, chunk = blockIdx.x & 15;
  const int b = bh >> 4, h = bh & 15;
  const int tid = threadIdx.x;

  for (int i = tid; i < 1024; i += 256)
    *(f32x4*)&kvs[i * 4] = *(const f32x4*)&kvm[(long)bh * 4096 + i * 4];
  if (tid < 16)
    *(f32x4*)&kss[tid * 4] = *(const f32x4*)&ksum[(long)bh * 64 + tid * 4];
  __syncthreads();

  const int i = chunk * 256 + tid;   // row within sequence
  const bf16* qrow = qp + ((long)(b * NSEQ + i)) * NC + h * ND;

  float s = 0.f;
#pragma unroll
  for (int c8 = 0; c8 < 8; ++c8) {
    bf16x8 q8 = *(const bf16x8*)(qrow + c8 * 8);
#pragma unroll
    for (int j = 0; j < 8; j++) s += (float)q8[j] * kss[c8 * 8 + j];
  }
  const float z = 1.0f / (s + EPSF);

  f32x4 o4[16] = {};
  for (int c8 = 0; c8 < 8; ++c8) {
    bf16x8 q8 = *(const bf16x8*)(qrow + c8 * 8);
#pragma unroll
    for (int j = 0; j < 8; j++) {
      float qc = (float)q8[j];
      const f32x4* kr = (const f32x4*)&kvs[(c8 * 8 + j) * 64];
#pragma unroll
      for (int d4 = 0; d4 < 16; ++d4) o4[d4] += qc * kr[d4];
    }
  }
  bf16* orow = ob + ((long)(b * NSEQ + i)) * NC + h * ND;
#pragma unroll
  for (int d4 = 0; d4 < 16; ++d4) {
    bf16x4 o;
#pragma unroll
    for (int j = 0; j < 4; j++) o[j] = (bf16)(o4[d4][j] * z);
    *(bf16x4*)(orow + d4 * 4) = o;
  }
}

// ---------------- launch ----------------
extern "C" void kernel_launch(void* const* d_in, const int* in_sizes, int n_in,
                              void* d_out, int out_size, void* d_ws, size_t ws_size,
                              hipStream_t stream) {
  const float* x = (const float*)d_in[0];
  const float* scale = (const float*)d_in[1];
  const float* pos_enc = (const float*)d_in[2];
  const float* qkv_w = (const float*)d_in[3];
  const float* proj_w = (const float*)d_in[4];
  const float* proj_b = (const float*)d_in[5];
  float* out = (float*)d_out;

  char* ws = (char*)d_ws;
  size_t off = 0;
  auto alloc = [&](size_t bytes) {
    char* p = ws + off;
    off += (bytes + 255) & ~(size_t)255;
    return p;
  };
  bf16* xb = (bf16*)alloc((size_t)NM * NC * 2);          // 64 MB (reused as qp)
  bf16* wqkv = (bf16*)alloc((size_t)3 * NC * NC * 2);    // 6 MB
  bf16* wproj = (bf16*)alloc((size_t)NC * NC * 2);       // 2 MB
  float* inv_sc = (float*)alloc(NC * 4);
  bf16* vb = (bf16*)alloc((size_t)NM * NC * 2);          // 64 MB
  bf16* kp = (bf16*)alloc((size_t)NM * NC * 2);          // 64 MB
  float* ks_part = (float*)alloc((size_t)KSPLIT * NBH * ND * 4);
  float* ksum = (float*)alloc((size_t)NBH * ND * 4);
  float* kvm = (float*)alloc((size_t)NBH * ND * ND * 4); // 2 MB
  float* qkf = (float*)alloc((size_t)NM * 2048 * 4);     // 256 MB (dead after transform)
  (void)ws_size; (void)n_in; (void)in_sizes; (void)out_size;

  // aliases into the qkf region (qkf is dead after transform_qk):
  bf16* ob = (bf16*)qkf;                                  // 64 MB
  float* kv_part = (float*)((char*)qkf + (size_t)NM * NC * 2); // 16 MB
  bf16* qp = xb;                                          // xb dead after gemm_qkv

  // 1. converts
  cvt_bf16<<<dim3((NM * NC / 4 + 255) / 256), 256, 0, stream>>>(x, xb, NM * NC / 4);
  cvt_bf16<<<dim3((3 * NC * NC / 4 + 255) / 256), 256, 0, stream>>>(qkv_w, wqkv, 3 * NC * NC / 4);
  cvt_bf16<<<dim3((NC * NC / 4 + 255) / 256), 256, 0, stream>>>(proj_w, wproj, NC * NC / 4);
  prep_scale<<<dim3(4), 256, 0, stream>>>(scale, inv_sc);

  // 2. qkv GEMM: (32768 x 1024) @ (3072 x 1024)^T
  gemm_bt<0><<<dim3(24, 256), 256, 0, stream>>>(xb, wqkv, NC, qkf, vb, nullptr);

  // 3. q/k transform
  transform_qk<<<dim3(NM), 256, 0, stream>>>(qkf, pos_enc, inv_sc, qp, kp);

  // 4. kv / ksum
  kv_partial<<<dim3(KSPLIT, NBH), 256, 0, stream>>>(kp, vb, kv_part, ks_part);
  reduce_parts<<<dim3((NBH * ND + 255) / 256), 256, 0, stream>>>(ks_part, ksum, NBH * ND);
  reduce_parts<<<dim3((NBH * 4096 + 255) / 256), 256, 0, stream>>>(kv_part, kvm, NBH * 4096);

  // 5. z + o
  z_o<<<dim3(NBH * 16), 256, 0, stream>>>(qp, kvm, ksum, ob);

  // 6. proj GEMM + bias
  gemm_bt<1><<<dim3(8, 256), 256, 0, stream>>>(ob, wproj, NC, out, nullptr, proj_b);
}

// Round 2
// 916.661 us; speedup vs baseline: 1.0239x; 1.0239x over previous
//
#include <hip/hip_runtime.h>
#include <hip/hip_bf16.h>
#include <cstdint>
#include <cstddef>

// FocusedLinearAttention on MI355X (gfx950).
// R2: qk stored bf16 (was fp32: -128MB write, -128MB read), packed-pair
// epilogue stores via shfl_xor (half the store instrs), pos_enc bf16.

typedef __bf16 bf16;
typedef __bf16 bf16x4 __attribute__((ext_vector_type(4)));
typedef __bf16 bf16x8 __attribute__((ext_vector_type(8)));
typedef float f32x4 __attribute__((ext_vector_type(4)));
typedef float f32x2 __attribute__((ext_vector_type(2)));

#define NB 8
#define NSEQ 4096
#define NC 1024
#define NH 16
#define ND 64
#define NBH 128      // NB*NH
#define NM 32768     // NB*NSEQ
#define EPSF 1e-6f
#define KSPLIT 8

__device__ __forceinline__ void async16(const void* g, void* l) {
  __builtin_amdgcn_global_load_lds(
      (const __attribute__((address_space(1))) void*)g,
      (__attribute__((address_space(3))) void*)l, 16, 0, 0);
}

__device__ __forceinline__ unsigned pack_bf16(float a, float b) {
  union { bf16 h[2]; unsigned u; } t;
  t.h[0] = (bf16)a; t.h[1] = (bf16)b;
  return t.u;
}

// ---------------- fp32 -> bf16 convert ----------------
__global__ __launch_bounds__(256) void cvt_bf16(const float* __restrict__ src,
                                                bf16* __restrict__ dst, int n4) {
  int i = blockIdx.x * 256 + threadIdx.x;
  if (i < n4) {
    f32x4 v = ((const f32x4*)src)[i];
    bf16x4 o;
    o[0] = (bf16)v[0]; o[1] = (bf16)v[1]; o[2] = (bf16)v[2]; o[3] = (bf16)v[3];
    ((bf16x4*)dst)[i] = o;
  }
}

// ---------------- inv softplus(scale) ----------------
__global__ __launch_bounds__(256) void prep_scale(const float* __restrict__ scale,
                                                  float* __restrict__ inv_sc) {
  int c = blockIdx.x * 256 + threadIdx.x;
  if (c < NC) inv_sc[c] = 1.0f / log1pf(expf(scale[c]));
}

// ---------------- 128x128 bf16 MFMA GEMM, C = A @ B^T ----------------
// A: (M x K) bf16 row-major, Bm: (N x K) bf16 row-major. K % 32 == 0.
// MODE 0: qkv. col < 2048 -> bf16 outqk (width 2048); col >= 2048 -> bf16 outv (1024)
// MODE 1: fp32 out width 1024, += bias
template <int MODE>
__global__ __launch_bounds__(256) void gemm_bt(const bf16* __restrict__ A,
                                               const bf16* __restrict__ Bm, int K,
                                               bf16* __restrict__ outqk,
                                               bf16* __restrict__ outv,
                                               float* __restrict__ outf,
                                               const float* __restrict__ bias) {
  __shared__ bf16 As[128 * 32];
  __shared__ bf16 Bs[128 * 32];
  const int tid = threadIdx.x;
  const int w = tid >> 6, lane = tid & 63;
  const int wm = (w >> 1) * 64, wn = (w & 1) * 64;
  const int q4 = lane >> 4, l16 = lane & 15;
  const long row0 = (long)blockIdx.y * 128, col0 = (long)blockIdx.x * 128;

  const int rA = w * 32 + (lane >> 2);   // staged row (chunk w*2), +16 for chunk w*2+1
  const int kkc = (lane & 3) * 8;        // k element offset within 32-wide tile
  const bf16* Ag = A + (row0 + rA) * (long)K + kkc;
  const bf16* Bg = Bm + (col0 + rA) * (long)K + kkc;
  bf16* Al = As + w * 1024 + lane * 8;
  bf16* Bl = Bs + w * 1024 + lane * 8;

  f32x4 acc[4][4] = {};

  for (int k0 = 0; k0 < K; k0 += 32) {
    async16(Ag + k0, Al);
    async16(Ag + 16 * (long)K + k0, Al + 512);
    async16(Bg + k0, Bl);
    async16(Bg + 16 * (long)K + k0, Bl + 512);
    __syncthreads();
    bf16x8 af[4], bfr[4];
#pragma unroll
    for (int mi = 0; mi < 4; mi++)
      af[mi] = *(const bf16x8*)(As + (wm + mi * 16 + l16) * 32 + q4 * 8);
#pragma unroll
    for (int ni = 0; ni < 4; ni++)
      bfr[ni] = *(const bf16x8*)(Bs + (wn + ni * 16 + l16) * 32 + q4 * 8);
#pragma unroll
    for (int mi = 0; mi < 4; mi++)
#pragma unroll
      for (int ni = 0; ni < 4; ni++)
        acc[mi][ni] = __builtin_amdgcn_mfma_f32_16x16x32_bf16(af[mi], bfr[ni],
                                                              acc[mi][ni], 0, 0, 0);
    __syncthreads();
  }

  // ---- packed-pair epilogue ----
  // C/D layout: lane(q4,l16) holds rows gr0..gr0+3 (gr0=row0+wm+mi*16+q4*4),
  // col gc. Exchange with lane^1 (adjacent column) -> each lane stores 2 rows
  // of a column PAIR as one dword (bf16) / dwordx2 (fp32).
  const int ev = (l16 & 1) == 0;
#pragma unroll
  for (int mi = 0; mi < 4; mi++) {
    long gr0 = row0 + wm + mi * 16 + q4 * 4;
#pragma unroll
    for (int ni = 0; ni < 4; ni++) {
      long gc = col0 + wn + ni * 16 + l16;
      long cb = gc & ~1L;
      long ra = gr0 + (ev ? 0 : 2);
      if (MODE == 0) {
        unsigned m01 = pack_bf16(acc[mi][ni][0], acc[mi][ni][1]);
        unsigned m23 = pack_bf16(acc[mi][ni][2], acc[mi][ni][3]);
        unsigned p01 = __shfl_xor(m01, 1);
        unsigned p23 = __shfl_xor(m23, 1);
        unsigned xs = ev ? m01 : p23;
        unsigned ys = ev ? p01 : m23;
        unsigned da = (xs & 0xFFFFu) | (ys << 16);
        unsigned db = (xs >> 16) | (ys & 0xFFFF0000u);
        if (col0 < 2048) {
          *(unsigned*)(outqk + ra * 2048 + cb) = da;
          *(unsigned*)(outqk + (ra + 1) * 2048 + cb) = db;
        } else {
          *(unsigned*)(outv + ra * 1024 + (cb - 2048)) = da;
          *(unsigned*)(outv + (ra + 1) * 1024 + (cb - 2048)) = db;
        }
      } else {
        float bsum = bias[gc];
        float v0 = acc[mi][ni][0] + bsum, v1 = acc[mi][ni][1] + bsum;
        float v2 = acc[mi][ni][2] + bsum, v3 = acc[mi][ni][3] + bsum;
        float p0 = __shfl_xor(v0, 1), p1 = __shfl_xor(v1, 1);
        float p2 = __shfl_xor(v2, 1), p3 = __shfl_xor(v3, 1);
        f32x2 sa, sb;
        sa[0] = ev ? v0 : p2; sa[1] = ev ? p0 : v2;
        sb[0] = ev ? v1 : p3; sb[1] = ev ? p1 : v3;
        *(f32x2*)(outf + ra * 1024 + cb) = sa;
        *(f32x2*)(outf + (ra + 1) * 1024 + cb) = sb;
      }
    }
  }
}

// ---------------- q/k nonlinear transform (per row over C=1024) ----------------
__global__ __launch_bounds__(256) void transform_qk(const bf16* __restrict__ qkb,
                                                    const bf16* __restrict__ peb,
                                                    const float* __restrict__ inv_sc,
                                                    bf16* __restrict__ qp,
                                                    bf16* __restrict__ kp) {
  __shared__ f32x4 red[4];
  const long row = blockIdx.x;          // 0..NM-1
  const int n = (int)(row & (NSEQ - 1));
  const int c0 = threadIdx.x * 4;

  bf16x4 qb = *(const bf16x4*)(qkb + row * 2048 + c0);
  bf16x4 kb = *(const bf16x4*)(qkb + row * 2048 + 1024 + c0);
  bf16x4 pe = *(const bf16x4*)(peb + (long)n * 1024 + c0);
  f32x4 isc = *(const f32x4*)(inv_sc + c0);

  f32x4 q3, k3;
  float s2q = 0, s6q = 0, s2k = 0, s6k = 0;
#pragma unroll
  for (int j = 0; j < 4; j++) {
    float qv = (fmaxf((float)qb[j], 0.f) + EPSF) * isc[j];
    float kv = (fmaxf((float)kb[j] + (float)pe[j], 0.f) + EPSF) * isc[j];
    float q3v = qv * qv * qv, k3v = kv * kv * kv;
    q3[j] = q3v; k3[j] = k3v;
    s2q += qv * qv; s6q += q3v * q3v;
    s2k += kv * kv; s6k += k3v * k3v;
  }
  f32x4 s; s[0] = s2q; s[1] = s6q; s[2] = s2k; s[3] = s6k;
#pragma unroll
  for (int off = 32; off > 0; off >>= 1) {
    s[0] += __shfl_xor(s[0], off);
    s[1] += __shfl_xor(s[1], off);
    s[2] += __shfl_xor(s[2], off);
    s[3] += __shfl_xor(s[3], off);
  }
  const int wv = threadIdx.x >> 6;
  if ((threadIdx.x & 63) == 0) red[wv] = s;
  __syncthreads();
  f32x4 tot = red[0] + red[1] + red[2] + red[3];
  float fq = sqrtf(tot[0] / tot[1]);
  float fk = sqrtf(tot[2] / tot[3]);

  bf16x4 qo, ko;
#pragma unroll
  for (int j = 0; j < 4; j++) {
    qo[j] = (bf16)(q3[j] * fq);
    ko[j] = (bf16)(k3[j] * fk);
  }
  *(bf16x4*)(qp + row * 1024 + c0) = qo;
  *(bf16x4*)(kp + row * 1024 + c0) = ko;
}

// ---------------- kv = k^T v and ksum, partial over N/KSPLIT rows ----------------
__global__ __launch_bounds__(256) void kv_partial(const bf16* __restrict__ kp,
                                                  const bf16* __restrict__ vb,
                                                  float* __restrict__ kv_part,
                                                  float* __restrict__ ks_part) {
  __shared__ float kls[64 * 64];
  __shared__ float vls[64 * 64];
  const int sp = blockIdx.x;       // 0..KSPLIT-1
  const int bh = blockIdx.y;       // 0..127
  const int b = bh >> 4, h = bh & 15;
  const int tid = threadIdx.x;
  const int c0 = (tid & 15) * 4, d0 = (tid >> 4) * 4;

  f32x4 acc4[4] = {};
  float ks[4] = {0.f, 0.f, 0.f, 0.f};

  for (int chunk = 0; chunk < NSEQ / KSPLIT / 64; ++chunk) {
    const int n0 = sp * (NSEQ / KSPLIT) + chunk * 64;
    __syncthreads();
    for (int it = tid; it < 1024; it += 256) {
      int nn = it >> 4, cc = (it & 15) * 4;
      long g = ((long)(b * NSEQ + n0 + nn)) * NC + h * ND + cc;
      bf16x4 kb = *(const bf16x4*)(kp + g);
      bf16x4 vv = *(const bf16x4*)(vb + g);
      f32x4 kf, vf;
#pragma unroll
      for (int j = 0; j < 4; j++) { kf[j] = (float)kb[j]; vf[j] = (float)vv[j]; }
      *(f32x4*)&kls[nn * 64 + cc] = kf;
      *(f32x4*)&vls[nn * 64 + cc] = vf;
    }
    __syncthreads();
    for (int nn = 0; nn < 64; ++nn) {
      f32x4 kk = *(const f32x4*)&kls[nn * 64 + c0];
      f32x4 vv = *(const f32x4*)&vls[nn * 64 + d0];
#pragma unroll
      for (int i = 0; i < 4; i++) acc4[i] += kk[i] * vv;
      if (tid < 16) {
#pragma unroll
        for (int i = 0; i < 4; i++) ks[i] += kk[i];
      }
    }
  }
  const long base = ((long)(sp * NBH + bh)) * 4096;
#pragma unroll
  for (int i = 0; i < 4; i++)
    *(f32x4*)&kv_part[base + (c0 + i) * 64 + d0] = acc4[i];
  if (tid < 16) {
#pragma unroll
    for (int i = 0; i < 4; i++)
      ks_part[(long)(sp * NBH + bh) * 64 + c0 + i] = ks[i];
  }
}

__global__ __launch_bounds__(256) void reduce_parts(const float* __restrict__ src,
                                                    float* __restrict__ dst, int n) {
  int i = blockIdx.x * 256 + threadIdx.x;
  if (i < n) {
    float s = 0.f;
    for (int p = 0; p < KSPLIT; ++p) s += src[(long)p * n + i];
    dst[i] = s;
  }
}

// ---------------- z + o = z * q' @ kv ----------------
__global__ __launch_bounds__(256) void z_o(const bf16* __restrict__ qp,
                                           const float* __restrict__ kvm,
                                           const float* __restrict__ ksum,
                                           bf16* __restrict__ ob) {
  __shared__ float kvs[4096];
  __shared__ float kss[64];
  const int bh = blockIdx.x >> 4, chunk = blockIdx.x & 15;
  const int b = bh >> 4, h = bh & 15;
  const int tid = threadIdx.x;

  for (int i = tid; i < 1024; i += 256)
    *(f32x4*)&kvs[i * 4] = *(const f32x4*)&kvm[(long)bh * 4096 + i * 4];
  if (tid < 16)
    *(f32x4*)&kss[tid * 4] = *(const f32x4*)&ksum[(long)bh * 64 + tid * 4];
  __syncthreads();

  const int i = chunk * 256 + tid;   // row within sequence
  const bf16* qrow = qp + ((long)(b * NSEQ + i)) * NC + h * ND;

  float s = 0.f;
#pragma unroll
  for (int c8 = 0; c8 < 8; ++c8) {
    bf16x8 q8 = *(const bf16x8*)(qrow + c8 * 8);
#pragma unroll
    for (int j = 0; j < 8; j++) s += (float)q8[j] * kss[c8 * 8 + j];
  }
  const float z = 1.0f / (s + EPSF);

  f32x4 o4[16] = {};
  for (int c8 = 0; c8 < 8; ++c8) {
    bf16x8 q8 = *(const bf16x8*)(qrow + c8 * 8);
#pragma unroll
    for (int j = 0; j < 8; j++) {
      float qc = (float)q8[j];
      const f32x4* kr = (const f32x4*)&kvs[(c8 * 8 + j) * 64];
#pragma unroll
      for (int d4 = 0; d4 < 16; ++d4) o4[d4] += qc * kr[d4];
    }
  }
  bf16* orow = ob + ((long)(b * NSEQ + i)) * NC + h * ND;
#pragma unroll
  for (int d4 = 0; d4 < 16; ++d4) {
    bf16x4 o;
#pragma unroll
    for (int j = 0; j < 4; j++) o[j] = (bf16)(o4[d4][j] * z);
    *(bf16x4*)(orow + d4 * 4) = o;
  }
}

// ---------------- launch ----------------
extern "C" void kernel_launch(void* const* d_in, const int* in_sizes, int n_in,
                              void* d_out, int out_size, void* d_ws, size_t ws_size,
                              hipStream_t stream) {
  const float* x = (const float*)d_in[0];
  const float* scale = (const float*)d_in[1];
  const float* pos_enc = (const float*)d_in[2];
  const float* qkv_w = (const float*)d_in[3];
  const float* proj_w = (const float*)d_in[4];
  const float* proj_b = (const float*)d_in[5];
  float* out = (float*)d_out;

  char* ws = (char*)d_ws;
  size_t off = 0;
  auto alloc = [&](size_t bytes) {
    char* p = ws + off;
    off += (bytes + 255) & ~(size_t)255;
    return p;
  };
  bf16* xb = (bf16*)alloc((size_t)NM * NC * 2);          // 64 MB (reused as qp)
  bf16* wqkv = (bf16*)alloc((size_t)3 * NC * NC * 2);    // 6 MB
  bf16* wproj = (bf16*)alloc((size_t)NC * NC * 2);       // 2 MB
  float* inv_sc = (float*)alloc(NC * 4);
  bf16* peb = (bf16*)alloc((size_t)NSEQ * NC * 2);       // 8 MB
  bf16* vb = (bf16*)alloc((size_t)NM * NC * 2);          // 64 MB
  bf16* kp = (bf16*)alloc((size_t)NM * NC * 2);          // 64 MB
  float* ks_part = (float*)alloc((size_t)KSPLIT * NBH * ND * 4);
  float* ksum = (float*)alloc((size_t)NBH * ND * 4);
  float* kvm = (float*)alloc((size_t)NBH * ND * ND * 4); // 2 MB
  bf16* qkb = (bf16*)alloc((size_t)NM * 2048 * 2);       // 128 MB (dead after transform)
  (void)ws_size; (void)n_in; (void)in_sizes; (void)out_size;

  // aliases into the qkb region (qkb is dead after transform_qk):
  bf16* ob = (bf16*)qkb;                                       // 64 MB
  float* kv_part = (float*)((char*)qkb + (size_t)NM * NC * 2); // 16 MB
  bf16* qp = xb;                                               // xb dead after gemm_qkv

  // 1. converts
  cvt_bf16<<<dim3((NM * NC / 4 + 255) / 256), 256, 0, stream>>>(x, xb, NM * NC / 4);
  cvt_bf16<<<dim3((3 * NC * NC / 4 + 255) / 256), 256, 0, stream>>>(qkv_w, wqkv, 3 * NC * NC / 4);
  cvt_bf16<<<dim3((NC * NC / 4 + 255) / 256), 256, 0, stream>>>(proj_w, wproj, NC * NC / 4);
  cvt_bf16<<<dim3((NSEQ * NC / 4 + 255) / 256), 256, 0, stream>>>(pos_enc, peb, NSEQ * NC / 4);
  prep_scale<<<dim3(4), 256, 0, stream>>>(scale, inv_sc);

  // 2. qkv GEMM: (32768 x 1024) @ (3072 x 1024)^T
  gemm_bt<0><<<dim3(24, 256), 256, 0, stream>>>(xb, wqkv, NC, qkb, vb, nullptr, nullptr);

  // 3. q/k transform
  transform_qk<<<dim3(NM), 256, 0, stream>>>(qkb, peb, inv_sc, qp, kp);

  // 4. kv / ksum
  kv_partial<<<dim3(KSPLIT, NBH), 256, 0, stream>>>(kp, vb, kv_part, ks_part);
  reduce_parts<<<dim3((NBH * ND + 255) / 256), 256, 0, stream>>>(ks_part, ksum, NBH * ND);
  reduce_parts<<<dim3((NBH * 4096 + 255) / 256), 256, 0, stream>>>(kv_part, kvm, NBH * 4096);

  // 5. z + o
  z_o<<<dim3(NBH * 16), 256, 0, stream>>>(qp, kvm, ksum, ob);

  // 6. proj GEMM + bias
  gemm_bt<1><<<dim3(8, 256), 256, 0, stream>>>(ob, wproj, NC, nullptr, nullptr, out, proj_b);
}